// Round 5
// baseline (218.183 us; speedup 1.0000x reference)
//
#include <hip/hip_runtime.h>

// NCA update, fused bf16-MFMA, barrier-free main loop.
//   out = W2 @ relu(Conv3x3(state; W1fold) + b1) + b2
// W1fold folds sobel_x/sobel_y/identity into one 16->128 3x3 conv:
// K = 144 (9 pos x 16 ch), b1 stored in spare col 144 of the stride-152 rows
// (B-fragment supplies bf16 1.0 at k=144 -> bias folded into GEMM1).
//
// Per block: 4 waves, region 16 rows x 64 cols, LDS = W1fold only (39 KB).
// Each wave owns rows r0+4t+wv (t=0..3), 64 px each as 4 tiles of 16.
// B-fragments (im2col) are built straight from global f32 loads (2x dwordx4
// + 4x v_cvt_pk per fragment) -- no state tile in LDS, NO __syncthreads in
// the main loop. Hidden transposed in-register (permlane32/16 swap), GEMM2
// fused. Grid = 1024 blocks = exactly 4/CU, XCD-swizzled.

constexpr int Hc = 1024, Wc = 1024;
constexpr int W1S = 152;       // shorts per W1fold row: 144 weights + b1 + 7 pad
constexpr int W1PAD = 19968;   // shorts: 128*152=19456 padded to 39*1024 B

typedef __attribute__((ext_vector_type(8))) short short8;
typedef __attribute__((ext_vector_type(4))) float f32x4;
typedef __attribute__((ext_vector_type(2))) unsigned int uint2v;

__device__ __forceinline__ unsigned short bfu(float x) {
    __bf16 b = (__bf16)x;                       // RNE
    return __builtin_bit_cast(unsigned short, b);
}
__device__ __forceinline__ unsigned pack2(float a, float b) {
    return (unsigned)bfu(a) | ((unsigned)bfu(b) << 16);
}

__device__ __forceinline__ void swap32(unsigned x, unsigned y, unsigned& o0, unsigned& o1) {
#if __has_builtin(__builtin_amdgcn_permlane32_swap)
    uint2v r = __builtin_amdgcn_permlane32_swap(x, y, false, false);
    o0 = r[0]; o1 = r[1];
#else
    unsigned xs = (unsigned)__shfl_xor((int)x, 32, 64);
    unsigned ys = (unsigned)__shfl_xor((int)y, 32, 64);
    const bool hi = (threadIdx.x & 32) != 0;
    o0 = hi ? ys : x;
    o1 = hi ? y : xs;
#endif
}
__device__ __forceinline__ void swap16(unsigned a, unsigned b, unsigned& o0, unsigned& o1) {
#if __has_builtin(__builtin_amdgcn_permlane16_swap)
    uint2v r = __builtin_amdgcn_permlane16_swap(a, b, false, false);
    o0 = r[0]; o1 = r[1];
#else
    unsigned as = (unsigned)__shfl_xor((int)a, 16, 64);
    unsigned bs = (unsigned)__shfl_xor((int)b, 16, 64);
    const bool hi = (threadIdx.x & 16) != 0;
    o0 = hi ? bs : a;
    o1 = hi ? b : as;
#endif
}

// ---------------- prep: W1fold (+b1) and W2 -> bf16 in ws ----------------
__global__ __launch_bounds__(256) void nca_prep(
    const float* __restrict__ W1c, const float* __restrict__ b1c,
    const float* __restrict__ W2c,
    unsigned short* __restrict__ ws1, unsigned short* __restrict__ ws2)
{
    const int u = blockIdx.x * 256 + threadIdx.x;
    if (u < W1PAD) {
        const int row = u / W1S, k = u - row * W1S;
        float v = 0.f;
        if (row < 128) {
            if (k < 144) {
                const int pos = k >> 4, c = k & 15;
                const int dy = pos / 3, dx = pos - dy * 3;
                v = (float)((dx - 1) * (1 + (dy == 1))) * W1c[row * 48 + c]
                  + (float)((dy - 1) * (1 + (dx == 1))) * W1c[row * 48 + 16 + c];
                if (pos == 4) v += W1c[row * 48 + 32 + c];
            } else if (k == 144) {
                v = b1c[row];
            }
        }
        ws1[u] = bfu(v);
    } else if (u < W1PAD + 16 * 128) {
        const int w = u - W1PAD;
        ws2[w] = bfu(W2c[w]);
    }
}

// ---------------- main ----------------
template <bool USE_WS>
__global__ __launch_bounds__(256, 3) void nca_main(
    const float* __restrict__ state,
    const float* __restrict__ W1c, const float* __restrict__ b1c,
    const float* __restrict__ W2c, const float* __restrict__ b2c,
    const unsigned short* __restrict__ ws1,   // W1fold bf16 [128][152] (+pad)
    const unsigned short* __restrict__ ws2,   // W2 bf16 [16][128]
    float* __restrict__ out)
{
    __shared__ short w1f[W1PAD];              // 39936 B

    const int tid  = threadIdx.x;
    const int lane = tid & 63;
    const int wv   = tid >> 6;
    const int p    = lane & 15;
    const int g    = lane >> 4;

    int bid = (int)blockIdx.x;
    bid = ((bid & 7) << 7) | (bid >> 3);      // XCD-contiguous row groups (1024%8==0)
    const int r0 = (bid >> 4) << 4;           // 64 rowgroups x 16 rows
    const int c0 = (bid & 15) << 6;           // 16 colgroups x 64 cols

    // ---- W1fold -> LDS (once per block) ----
    if (USE_WS) {
        #pragma unroll
        for (int it = 0; it < 10; ++it) {
            const int chunk = it * 4 + wv;               // 39 x 1KB chunks
            if (chunk < 39) {
                const int off = chunk * 1024;
                __builtin_amdgcn_global_load_lds(
                    (const __attribute__((address_space(1))) unsigned int*)
                        ((const char*)ws1 + off + lane * 16),
                    (__attribute__((address_space(3))) unsigned int*)
                        ((char*)w1f + off),
                    16, 0, 0);
            }
        }
    } else {
        for (int u = tid; u < W1PAD; u += 256) {
            const int row = u / W1S, k = u - row * W1S;
            float v = 0.f;
            if (row < 128) {
                if (k < 144) {
                    const int pos = k >> 4, c = k & 15;
                    const int dy = pos / 3, dx = pos - dy * 3;
                    v = (float)((dx - 1) * (1 + (dy == 1))) * W1c[row * 48 + c]
                      + (float)((dy - 1) * (1 + (dx == 1))) * W1c[row * 48 + 16 + c];
                    if (pos == 4) v += W1c[row * 48 + 32 + c];
                } else if (k == 144) {
                    v = b1c[row];
                }
            }
            w1f[u] = (short)bfu(v);
        }
    }

    // ---- per-lane im2col constants ----
    // k-chunk i (i<4): halfpos = 4i+g -> pos = 2i + (g>>1), ch-half = g&1
    // i=4: pos = 8 (dy=2,dx=2), ch-half = g (loads only for g<2);
    //      g==2 supplies bf16 1.0 at k=144 (b1), g==3 zero.
    const int gb = g & 1;
    unsigned colpk[10] = {0, 0, 0, 0, 0, 0, 0, 0, 0, 0};
    unsigned dypk = 0;
    {
        const int cbase = c0 - 1 + p;
        #pragma unroll
        for (int i = 0; i < 5; ++i) {
            const int pos = (i < 4) ? (2 * i + (g >> 1)) : 8;
            const int dy = pos / 3, dx = pos - 3 * dy;
            dypk |= (unsigned)dy << (2 * i);
            #pragma unroll
            for (int pt = 0; pt < 4; ++pt) {
                const unsigned cbyte =
                    ((unsigned)((cbase + dx + 16 * pt) & (Wc - 1)) << 6) | ((unsigned)gb << 5);
                const int j = pt * 5 + i;
                colpk[j >> 1] |= cbyte << (16 * (j & 1));
            }
        }
    }

    // ---- W2 fragments + b2 (registers) ----
    short8 w2f[4];
    if (USE_WS) {
        const unsigned short* wsp = ws2 + p * 128 + 8 * g;
        #pragma unroll
        for (int kc = 0; kc < 4; ++kc)
            w2f[kc] = *reinterpret_cast<const short8*>(wsp + 32 * kc);
    } else {
        #pragma unroll
        for (int kc = 0; kc < 4; ++kc) {
            const float* qp = W2c + p * 128 + 32 * kc + 8 * g;
            const float4 A = *reinterpret_cast<const float4*>(qp);
            const float4 B = *reinterpret_cast<const float4*>(qp + 4);
            uint4 uu{pack2(A.x, A.y), pack2(A.z, A.w), pack2(B.x, B.y), pack2(B.z, B.w)};
            w2f[kc] = __builtin_bit_cast(short8, uu);
        }
    }
    const float4 bv = *reinterpret_cast<const float4*>(b2c + 4 * g);

    int ocol[4];
    #pragma unroll
    for (int pt = 0; pt < 4; ++pt) ocol[pt] = ((c0 + 16 * pt + p) << 6) + (g << 4);
    const int abase = p * W1S + 8 * g;        // short index into w1f

    const char* stby = (const char*)state;
    char* outby = (char*)out;

    __syncthreads();                          // w1f ready; no barriers after this

    #pragma unroll 1
    for (int t = 0; t < 4; ++t) {
        const int rbase = r0 + 4 * t + wv - 1;
        unsigned rowb[5];
        #pragma unroll
        for (int i = 0; i < 5; ++i)
            rowb[i] = (unsigned)((rbase + (int)((dypk >> (2 * i)) & 3u)) & (Hc - 1)) << 16;

        const long orow = (long)(r0 + 4 * t + wv) << 16;

        #pragma unroll
        for (int ptg = 0; ptg < 2; ++ptg) {
            // B fragments for 2 pixel-tiles, straight from global f32
            short8 bf[2][5];
            #pragma unroll
            for (int pp = 0; pp < 2; ++pp) {
                #pragma unroll
                for (int i = 0; i < 5; ++i) {
                    const int j = (2 * ptg + pp) * 5 + i;
                    const unsigned off =
                        rowb[i] + ((colpk[j >> 1] >> (16 * (j & 1))) & 0xffffu);
                    if (i < 4) {
                        const float4 A0 = *reinterpret_cast<const float4*>(stby + off);
                        const float4 A1 = *reinterpret_cast<const float4*>(stby + off + 16);
                        uint4 uu{pack2(A0.x, A0.y), pack2(A0.z, A0.w),
                                 pack2(A1.x, A1.y), pack2(A1.z, A1.w)};
                        bf[pp][i] = __builtin_bit_cast(short8, uu);
                    } else {
                        if (g < 2) {
                            const float4 A0 = *reinterpret_cast<const float4*>(stby + off);
                            const float4 A1 = *reinterpret_cast<const float4*>(stby + off + 16);
                            uint4 uu{pack2(A0.x, A0.y), pack2(A0.z, A0.w),
                                     pack2(A1.x, A1.y), pack2(A1.z, A1.w)};
                            bf[pp][i] = __builtin_bit_cast(short8, uu);
                        } else if (g == 2) {
                            uint4 uu{0x3F80u, 0u, 0u, 0u};   // bf16 1.0 @ k=144 (b1)
                            bf[pp][i] = __builtin_bit_cast(short8, uu);
                        } else {
                            uint4 uu{0u, 0u, 0u, 0u};
                            bf[pp][i] = __builtin_bit_cast(short8, uu);
                        }
                    }
                }
            }

            f32x4 acc2[2];
            #pragma unroll
            for (int pp = 0; pp < 2; ++pp) {
                acc2[pp][0] = bv.x; acc2[pp][1] = bv.y;
                acc2[pp][2] = bv.z; acc2[pp][3] = bv.w;
            }

            #pragma unroll
            for (int half = 0; half < 2; ++half) {
                #pragma unroll
                for (int tg = 0; tg < 2; ++tg) {
                    short8 Ar0[5], Ar1[5];
                    const int rofs = abase + (64 * half + 32 * tg) * W1S;
                    #pragma unroll
                    for (int i = 0; i < 5; ++i) {
                        Ar0[i] = *reinterpret_cast<const short8*>(&w1f[rofs + 32 * i]);
                        Ar1[i] = *reinterpret_cast<const short8*>(&w1f[rofs + 16 * W1S + 32 * i]);
                    }
                    #pragma unroll
                    for (int pp = 0; pp < 2; ++pp) {
                        f32x4 h0 = {0.f, 0.f, 0.f, 0.f}, h1 = {0.f, 0.f, 0.f, 0.f};
                        #pragma unroll
                        for (int i = 0; i < 5; ++i) {
                            h0 = __builtin_amdgcn_mfma_f32_16x16x32_bf16(Ar0[i], bf[pp][i], h0, 0, 0, 0);
                            h1 = __builtin_amdgcn_mfma_f32_16x16x32_bf16(Ar1[i], bf[pp][i], h1, 0, 0, 0);
                        }
                        // relu -> pack -> in-register transpose -> GEMM2
                        const unsigned Pa0 = pack2(fmaxf(h0[0], 0.f), fmaxf(h0[1], 0.f));
                        const unsigned Pa1 = pack2(fmaxf(h0[2], 0.f), fmaxf(h0[3], 0.f));
                        const unsigned Pb0 = pack2(fmaxf(h1[0], 0.f), fmaxf(h1[1], 0.f));
                        const unsigned Pb1 = pack2(fmaxf(h1[2], 0.f), fmaxf(h1[3], 0.f));
                        unsigned s0, s1, t0, t1, u0, u1, u2, u3;
                        swap32(Pa0, Pb0, s0, s1);
                        swap16(s0, s1, u0, u2);
                        swap32(Pa1, Pb1, t0, t1);
                        swap16(t0, t1, u1, u3);
                        uint4 uu{u0, u1, u2, u3};
                        acc2[pp] = __builtin_amdgcn_mfma_f32_16x16x32_bf16(
                            w2f[2 * half + tg], __builtin_bit_cast(short8, uu), acc2[pp], 0, 0, 0);
                    }
                }
            }

            #pragma unroll
            for (int pp = 0; pp < 2; ++pp) {
                float4 o;
                o.x = acc2[pp][0]; o.y = acc2[pp][1];
                o.z = acc2[pp][2]; o.w = acc2[pp][3];
                *reinterpret_cast<float4*>(outby + orow + ocol[2 * ptg + pp]) = o;
            }
        }
    }
}

extern "C" void kernel_launch(void* const* d_in, const int* in_sizes, int n_in,
                              void* d_out, int out_size, void* d_ws, size_t ws_size,
                              hipStream_t stream) {
    const float* state = (const float*)d_in[0];
    const float* W1c   = (const float*)d_in[1];
    const float* b1c   = (const float*)d_in[2];
    const float* W2c   = (const float*)d_in[3];
    const float* b2c   = (const float*)d_in[4];
    float* out = (float*)d_out;

    unsigned short* ws1 = (unsigned short*)d_ws;
    unsigned short* ws2 = ws1 + W1PAD;
    const size_t ws_needed = (size_t)(W1PAD + 16 * 128) * sizeof(unsigned short);

    if (ws_size >= ws_needed) {
        nca_prep<<<(W1PAD + 16 * 128 + 255) / 256, 256, 0, stream>>>(W1c, b1c, W2c, ws1, ws2);
        nca_main<true><<<1024, 256, 0, stream>>>(state, W1c, b1c, W2c, b2c, ws1, ws2, out);
    } else {
        nca_main<false><<<1024, 256, 0, stream>>>(state, W1c, b1c, W2c, b2c, ws1, ws2, out);
    }
}

// Round 7
// 127.880 us; speedup vs baseline: 1.7062x; 1.7062x over previous
//
#include <hip/hip_runtime.h>

// NCA update, fused bf16-MFMA, 3-blocks/CU occupancy version.
//   out = W2 @ relu(Conv3x3(state; W1fold) + b1) + b2
// W1fold folds sobel_x/sobel_y/identity into one 16->128 3x3 conv (K=144,
// b1 at col 144 of stride-152 rows; B supplies bf16 1.0 at k=144).
//
// Per block: 4 waves, region 16 rows x 64 cols (4 tiles of 4 rows).
// LDS: W1fold 39.9KB + single-buffered bf16 state tile 12.7KB = 52.6KB
// -> 3 blocks/CU. Tile is XOR-swizzled (byte ^= (pidx&4)<<2) so stride-32B
// pixel reads are bank-conflict-free. T14 staging: next tile's global loads
// issued before compute, cvt+ds_write after barrier. 2 barriers/tile.
// Hidden transposed in-register (permlane32/16 swap), GEMM2 fused.
// Staging: 792 16B-chunks = 3 full slots (768) + 24-chunk tail (tid<24).

constexpr int Hc = 1024, Wc = 1024;
constexpr int W1S = 152;       // shorts per W1fold row: 144 weights + b1 + 7 pad
constexpr int W1PAD = 19968;   // shorts: 128*152=19456, padded to 39*1024 B

typedef __attribute__((ext_vector_type(8))) short short8;
typedef __attribute__((ext_vector_type(4))) float f32x4;
typedef __attribute__((ext_vector_type(2))) unsigned int uint2v;

__device__ __forceinline__ unsigned short bfu(float x) {
    __bf16 b = (__bf16)x;                       // RNE
    return __builtin_bit_cast(unsigned short, b);
}
__device__ __forceinline__ unsigned pack2(float a, float b) {
    return (unsigned)bfu(a) | ((unsigned)bfu(b) << 16);
}

__device__ __forceinline__ void swap32(unsigned x, unsigned y, unsigned& o0, unsigned& o1) {
#if __has_builtin(__builtin_amdgcn_permlane32_swap)
    uint2v r = __builtin_amdgcn_permlane32_swap(x, y, false, false);
    o0 = r[0]; o1 = r[1];
#else
    unsigned xs = (unsigned)__shfl_xor((int)x, 32, 64);
    unsigned ys = (unsigned)__shfl_xor((int)y, 32, 64);
    const bool hi = (threadIdx.x & 32) != 0;
    o0 = hi ? ys : x;
    o1 = hi ? y : xs;
#endif
}
__device__ __forceinline__ void swap16(unsigned a, unsigned b, unsigned& o0, unsigned& o1) {
#if __has_builtin(__builtin_amdgcn_permlane16_swap)
    uint2v r = __builtin_amdgcn_permlane16_swap(a, b, false, false);
    o0 = r[0]; o1 = r[1];
#else
    unsigned as = (unsigned)__shfl_xor((int)a, 16, 64);
    unsigned bs = (unsigned)__shfl_xor((int)b, 16, 64);
    const bool hi = (threadIdx.x & 16) != 0;
    o0 = hi ? bs : a;
    o1 = hi ? b : as;
#endif
}

// ---------------- prep: W1fold (+b1) and W2 -> bf16 in ws ----------------
__global__ __launch_bounds__(256) void nca_prep(
    const float* __restrict__ W1c, const float* __restrict__ b1c,
    const float* __restrict__ W2c,
    unsigned short* __restrict__ ws1, unsigned short* __restrict__ ws2)
{
    const int u = blockIdx.x * 256 + threadIdx.x;
    if (u < W1PAD) {
        const int row = u / W1S, k = u - row * W1S;
        float v = 0.f;
        if (row < 128) {
            if (k < 144) {
                const int pos = k >> 4, c = k & 15;
                const int dy = pos / 3, dx = pos - dy * 3;
                v = (float)((dx - 1) * (1 + (dy == 1))) * W1c[row * 48 + c]
                  + (float)((dy - 1) * (1 + (dx == 1))) * W1c[row * 48 + 16 + c];
                if (pos == 4) v += W1c[row * 48 + 32 + c];
            } else if (k == 144) {
                v = b1c[row];
            }
        }
        ws1[u] = bfu(v);
    } else if (u < W1PAD + 16 * 128) {
        const int w = u - W1PAD;
        ws2[w] = bfu(W2c[w]);
    }
}

// ---------------- main ----------------
template <bool USE_WS>
__global__ __launch_bounds__(256, 3) void nca_main(
    const float* __restrict__ state,
    const float* __restrict__ W1c, const float* __restrict__ b1c,
    const float* __restrict__ W2c, const float* __restrict__ b2c,
    const unsigned short* __restrict__ ws1,   // W1fold bf16 [128][152] (+pad)
    const unsigned short* __restrict__ ws2,   // W2 bf16 [16][128]
    float* __restrict__ out)
{
    __shared__ short w1f[W1PAD];              // 39936 B
    __shared__ short tile[6 * 66 * 16];       // 12672 B, 32B/pixel, XOR-swizzled

    const int tid  = threadIdx.x;
    const int lane = tid & 63;
    const int wv   = tid >> 6;
    const int p    = lane & 15;
    const int g    = lane >> 4;

    const int bid = (int)blockIdx.x;          // natural mapping: XCD column stripes
    const int r0 = (bid >> 4) << 4;           // 64 rowgroups x 16 rows
    const int c0 = (bid & 15) << 6;           // 16 colgroups x 64 cols

    // ---- W1fold -> LDS (once per block) ----
    if (USE_WS) {
        #pragma unroll
        for (int it = 0; it < 10; ++it) {
            const int chunk = it * 4 + wv;               // 39 x 1KB chunks
            if (chunk < 39) {
                const int off = chunk * 1024;
                __builtin_amdgcn_global_load_lds(
                    (const __attribute__((address_space(1))) unsigned int*)
                        ((const char*)ws1 + off + lane * 16),
                    (__attribute__((address_space(3))) unsigned int*)
                        ((char*)w1f + off),
                    16, 0, 0);
            }
        }
    } else {
        for (int u = tid; u < W1PAD; u += 256) {
            const int row = u / W1S, k = u - row * W1S;
            float v = 0.f;
            if (row < 128) {
                if (k < 144) {
                    const int pos = k >> 4, c = k & 15;
                    const int dy = pos / 3, dx = pos - dy * 3;
                    v = (float)((dx - 1) * (1 + (dy == 1))) * W1c[row * 48 + c]
                      + (float)((dy - 1) * (1 + (dx == 1))) * W1c[row * 48 + 16 + c];
                    if (pos == 4) v += W1c[row * 48 + 32 + c];
                } else if (k == 144) {
                    v = b1c[row];
                }
            }
            w1f[u] = (short)bfu(v);
        }
    }

    // ---- staging constants: 792 16B-chunks = 3*256 + 24 (slot 3, tid<24) ----
    // chunk j: pixel pidx=j>>1 (row tr=pidx/66, col tc=pidx%66), half hb=j&1.
    // LDS byte = j*16 ^ ((j&8)<<1)   (the (pidx&4)<<2 swizzle).
    int grow[4], gcol[4], lofs[4];
    #pragma unroll
    for (int s = 0; s < 4; ++s) {
        const int j = tid + 256 * s;
        const int jj = (j < 792) ? j : 791;
        const int pidx = jj >> 1, hb = jj & 1;
        const int tr = pidx / 66, tc = pidx - tr * 66;
        grow[s] = tr;
        gcol[s] = (((c0 - 1 + tc) & (Wc - 1)) << 6) + (hb << 5);   // bytes
        lofs[s] = (jj * 16) ^ ((jj & 8) << 1);                      // bytes
    }
    const bool has3 = (tid < 24);

    // ---- W2 fragments + b2 (registers) ----
    short8 w2f[4];
    if (USE_WS) {
        const unsigned short* wsp = ws2 + p * 128 + 8 * g;
        #pragma unroll
        for (int kc = 0; kc < 4; ++kc)
            w2f[kc] = *reinterpret_cast<const short8*>(wsp + 32 * kc);
    } else {
        #pragma unroll
        for (int kc = 0; kc < 4; ++kc) {
            const float* qp = W2c + p * 128 + 32 * kc + 8 * g;
            const float4 A = *reinterpret_cast<const float4*>(qp);
            const float4 B = *reinterpret_cast<const float4*>(qp + 4);
            uint4 uu{pack2(A.x, A.y), pack2(A.z, A.w), pack2(B.x, B.y), pack2(B.z, B.w)};
            w2f[kc] = __builtin_bit_cast(short8, uu);
        }
    }
    const float4 bv = *reinterpret_cast<const float4*>(b2c + 4 * g);

    // ---- per-lane im2col B addresses (tile-local, constant across t) ----
    // chunk i<4: pos = 2i + (g>>1), ch-half gb = g&1. i=4: pos 8 (g<2);
    // g==2 -> bf16 1.0 at k=144 (b1 fold); g==3 -> zeros.
    const int gb = g & 1;
    int baddr[5];
    #pragma unroll
    for (int i = 0; i < 5; ++i) {
        const int pos = (i < 4) ? (2 * i + (g >> 1)) : 8;
        const int dy = pos / 3, dx = pos - 3 * dy;
        const int pidx = (wv + dy) * 66 + (p + dx);
        baddr[i] = (pidx * 32 + gb * 16) ^ ((pidx & 4) << 2);      // bytes
    }
    const int abase = p * W1S + 8 * g;        // short index into w1f

    int ocol[4];
    #pragma unroll
    for (int pt = 0; pt < 4; ++pt) ocol[pt] = ((c0 + 16 * pt + p) << 6) + (g << 4);

    const char* stby = (const char*)state;
    const char* tby  = (const char*)tile;
    char* outby = (char*)out;

    // ---- prologue: stage tile for t=0 (input rows r0-1 .. r0+4) ----
    {
        float4 sa[4], sb[4];
        #pragma unroll
        for (int s = 0; s < 4; ++s) {
            if (s < 3 || has3) {
                const long sr = (long)((r0 - 1 + grow[s]) & (Hc - 1));
                const char* bp = stby + (sr << 16) + gcol[s];
                sa[s] = *reinterpret_cast<const float4*>(bp);
                sb[s] = *reinterpret_cast<const float4*>(bp + 16);
            }
        }
        #pragma unroll
        for (int s = 0; s < 4; ++s) {
            if (s < 3 || has3) {
                uint4 uu{pack2(sa[s].x, sa[s].y), pack2(sa[s].z, sa[s].w),
                         pack2(sb[s].x, sb[s].y), pack2(sb[s].z, sb[s].w)};
                *reinterpret_cast<uint4*>((char*)tile + lofs[s]) = uu;
            }
        }
    }
    __syncthreads();

    #pragma unroll 1
    for (int t = 0; t < 4; ++t) {
        // (a) T14: issue next tile's global loads
        float4 sa[4], sb[4];
        if (t < 3) {
            const int rb = r0 + 4 * (t + 1) - 1;
            #pragma unroll
            for (int s = 0; s < 4; ++s) {
                if (s < 3 || has3) {
                    const long sr = (long)((rb + grow[s]) & (Hc - 1));
                    const char* bp = stby + (sr << 16) + gcol[s];
                    sa[s] = *reinterpret_cast<const float4*>(bp);
                    sb[s] = *reinterpret_cast<const float4*>(bp + 16);
                }
            }
        }

        // (b) compute current tile
        f32x4 acc2[4];
        #pragma unroll
        for (int pt = 0; pt < 4; ++pt) {
            acc2[pt][0] = bv.x; acc2[pt][1] = bv.y; acc2[pt][2] = bv.z; acc2[pt][3] = bv.w;
        }

        #pragma unroll
        for (int half = 0; half < 2; ++half) {
            short8 Ar[4][5];   // 4 hidden-tiles x 5 k-chunks
            #pragma unroll
            for (int tt = 0; tt < 4; ++tt) {
                #pragma unroll
                for (int i = 0; i < 5; ++i) {
                    Ar[tt][i] = *reinterpret_cast<const short8*>(
                        &w1f[abase + (64 * half + 16 * tt) * W1S + 32 * i]);
                }
            }

            __builtin_amdgcn_s_setprio(1);
            #pragma unroll
            for (int pt = 0; pt < 4; ++pt) {
                short8 bf[5];
                #pragma unroll
                for (int i = 0; i < 5; ++i) {
                    if (i < 4) {
                        bf[i] = *reinterpret_cast<const short8*>(tby + baddr[i] + pt * 512);
                    } else {
                        if (g < 2) {
                            bf[i] = *reinterpret_cast<const short8*>(tby + baddr[4] + pt * 512);
                        } else if (g == 2) {
                            uint4 uu{0x3F80u, 0u, 0u, 0u};   // bf16 1.0 @ k=144 (b1)
                            bf[i] = __builtin_bit_cast(short8, uu);
                        } else {
                            uint4 uu{0u, 0u, 0u, 0u};
                            bf[i] = __builtin_bit_cast(short8, uu);
                        }
                    }
                }

                f32x4 h[4];
                #pragma unroll
                for (int tt = 0; tt < 4; ++tt) h[tt] = (f32x4){0.f, 0.f, 0.f, 0.f};
                #pragma unroll
                for (int i = 0; i < 5; ++i) {
                    #pragma unroll
                    for (int tt = 0; tt < 4; ++tt)
                        h[tt] = __builtin_amdgcn_mfma_f32_16x16x32_bf16(Ar[tt][i], bf[i], h[tt], 0, 0, 0);
                }

                // relu -> pack -> in-register transpose -> GEMM2
                #pragma unroll
                for (int pr = 0; pr < 2; ++pr) {
                    const f32x4 ha = h[2 * pr], hc = h[2 * pr + 1];
                    const unsigned Pa0 = pack2(fmaxf(ha[0], 0.f), fmaxf(ha[1], 0.f));
                    const unsigned Pa1 = pack2(fmaxf(ha[2], 0.f), fmaxf(ha[3], 0.f));
                    const unsigned Pb0 = pack2(fmaxf(hc[0], 0.f), fmaxf(hc[1], 0.f));
                    const unsigned Pb1 = pack2(fmaxf(hc[2], 0.f), fmaxf(hc[3], 0.f));
                    unsigned s0, s1, t0, t1, u0, u1, u2, u3;
                    swap32(Pa0, Pb0, s0, s1);
                    swap16(s0, s1, u0, u2);
                    swap32(Pa1, Pb1, t0, t1);
                    swap16(t0, t1, u1, u3);
                    uint4 uu{u0, u1, u2, u3};
                    acc2[pt] = __builtin_amdgcn_mfma_f32_16x16x32_bf16(
                        w2f[2 * half + pr], __builtin_bit_cast(short8, uu), acc2[pt], 0, 0, 0);
                }
            }
            __builtin_amdgcn_s_setprio(0);
        }

        // (c) store output row
        const long orow = (long)(r0 + 4 * t + wv) << 16;
        #pragma unroll
        for (int pt = 0; pt < 4; ++pt) {
            float4 o; o.x = acc2[pt][0]; o.y = acc2[pt][1]; o.z = acc2[pt][2]; o.w = acc2[pt][3];
            *reinterpret_cast<float4*>(outby + orow + ocol[pt]) = o;
        }

        // (d) barrier (tile reads done) -> write next tile -> barrier
        if (t < 3) {
            __syncthreads();
            #pragma unroll
            for (int s = 0; s < 4; ++s) {
                if (s < 3 || has3) {
                    uint4 uu{pack2(sa[s].x, sa[s].y), pack2(sa[s].z, sa[s].w),
                             pack2(sb[s].x, sb[s].y), pack2(sb[s].z, sb[s].w)};
                    *reinterpret_cast<uint4*>((char*)tile + lofs[s]) = uu;
                }
            }
            __syncthreads();
        }
    }
}

extern "C" void kernel_launch(void* const* d_in, const int* in_sizes, int n_in,
                              void* d_out, int out_size, void* d_ws, size_t ws_size,
                              hipStream_t stream) {
    const float* state = (const float*)d_in[0];
    const float* W1c   = (const float*)d_in[1];
    const float* b1c   = (const float*)d_in[2];
    const float* W2c   = (const float*)d_in[3];
    const float* b2c   = (const float*)d_in[4];
    float* out = (float*)d_out;

    unsigned short* ws1 = (unsigned short*)d_ws;
    unsigned short* ws2 = ws1 + W1PAD;
    const size_t ws_needed = (size_t)(W1PAD + 16 * 128) * sizeof(unsigned short);

    if (ws_size >= ws_needed) {
        nca_prep<<<(W1PAD + 16 * 128 + 255) / 256, 256, 0, stream>>>(W1c, b1c, W2c, ws1, ws2);
        nca_main<true><<<1024, 256, 0, stream>>>(state, W1c, b1c, W2c, b2c, ws1, ws2, out);
    } else {
        nca_main<false><<<1024, 256, 0, stream>>>(state, W1c, b1c, W2c, b2c, ws1, ws2, out);
    }
}

// Round 8
// 76.370 us; speedup vs baseline: 2.8569x; 1.6745x over previous
//
#include <hip/hip_runtime.h>

// NCA update, fused bf16-MFMA.
//   out = W2 @ relu(Conv3x3(state; W1fold) + b1) + b2
// W1fold folds sobel_x/sobel_y/identity into one 16->128 3x3 conv (K=144,
// b1 at col 144 of stride-152 rows; B supplies bf16 1.0 at k=144).
//
// Per block: 4 waves, region 16 rows x 64 cols (4 tiles of 4 rows).
// LDS: W1fold 39.9KB + single-buffered bf16 state tile 12.7KB = 52.6KB
// -> 3 blocks/CU. Tile XOR-swizzled (byte ^= (pidx&4)<<2): stride-32B pixel
// reads ~conflict-free. Staging loads issued after compute (short liveness;
// R7's held-across-compute version spilled at the (256,3) VGPR cap ->
// 228MB scratch write traffic). launch_bounds (256,2): proven regalloc.
// Hidden transposed in-register (permlane32/16 swap), GEMM2 fused.

constexpr int Hc = 1024, Wc = 1024;
constexpr int W1S = 152;       // shorts per W1fold row: 144 weights + b1 + 7 pad
constexpr int W1PAD = 19968;   // shorts: 128*152=19456, padded to 39*1024 B

typedef __attribute__((ext_vector_type(8))) short short8;
typedef __attribute__((ext_vector_type(4))) float f32x4;
typedef __attribute__((ext_vector_type(2))) unsigned int uint2v;

__device__ __forceinline__ unsigned short bfu(float x) {
    __bf16 b = (__bf16)x;                       // RNE
    return __builtin_bit_cast(unsigned short, b);
}
__device__ __forceinline__ unsigned pack2(float a, float b) {
    return (unsigned)bfu(a) | ((unsigned)bfu(b) << 16);
}

__device__ __forceinline__ void swap32(unsigned x, unsigned y, unsigned& o0, unsigned& o1) {
#if __has_builtin(__builtin_amdgcn_permlane32_swap)
    uint2v r = __builtin_amdgcn_permlane32_swap(x, y, false, false);
    o0 = r[0]; o1 = r[1];
#else
    unsigned xs = (unsigned)__shfl_xor((int)x, 32, 64);
    unsigned ys = (unsigned)__shfl_xor((int)y, 32, 64);
    const bool hi = (threadIdx.x & 32) != 0;
    o0 = hi ? ys : x;
    o1 = hi ? y : xs;
#endif
}
__device__ __forceinline__ void swap16(unsigned a, unsigned b, unsigned& o0, unsigned& o1) {
#if __has_builtin(__builtin_amdgcn_permlane16_swap)
    uint2v r = __builtin_amdgcn_permlane16_swap(a, b, false, false);
    o0 = r[0]; o1 = r[1];
#else
    unsigned as = (unsigned)__shfl_xor((int)a, 16, 64);
    unsigned bs = (unsigned)__shfl_xor((int)b, 16, 64);
    const bool hi = (threadIdx.x & 16) != 0;
    o0 = hi ? bs : a;
    o1 = hi ? b : as;
#endif
}

// ---------------- prep: W1fold (+b1) and W2 -> bf16 in ws ----------------
__global__ __launch_bounds__(256) void nca_prep(
    const float* __restrict__ W1c, const float* __restrict__ b1c,
    const float* __restrict__ W2c,
    unsigned short* __restrict__ ws1, unsigned short* __restrict__ ws2)
{
    const int u = blockIdx.x * 256 + threadIdx.x;
    if (u < W1PAD) {
        const int row = u / W1S, k = u - row * W1S;
        float v = 0.f;
        if (row < 128) {
            if (k < 144) {
                const int pos = k >> 4, c = k & 15;
                const int dy = pos / 3, dx = pos - dy * 3;
                v = (float)((dx - 1) * (1 + (dy == 1))) * W1c[row * 48 + c]
                  + (float)((dy - 1) * (1 + (dx == 1))) * W1c[row * 48 + 16 + c];
                if (pos == 4) v += W1c[row * 48 + 32 + c];
            } else if (k == 144) {
                v = b1c[row];
            }
        }
        ws1[u] = bfu(v);
    } else if (u < W1PAD + 16 * 128) {
        const int w = u - W1PAD;
        ws2[w] = bfu(W2c[w]);
    }
}

// ---------------- main ----------------
template <bool USE_WS>
__global__ __launch_bounds__(256, 2) void nca_main(
    const float* __restrict__ state,
    const float* __restrict__ W1c, const float* __restrict__ b1c,
    const float* __restrict__ W2c, const float* __restrict__ b2c,
    const unsigned short* __restrict__ ws1,   // W1fold bf16 [128][152] (+pad)
    const unsigned short* __restrict__ ws2,   // W2 bf16 [16][128]
    float* __restrict__ out)
{
    __shared__ short w1f[W1PAD];              // 39936 B
    __shared__ short tile[6 * 66 * 16];       // 12672 B, 32B/pixel, XOR-swizzled

    const int tid  = threadIdx.x;
    const int lane = tid & 63;
    const int wv   = tid >> 6;
    const int p    = lane & 15;
    const int g    = lane >> 4;

    const int bid = (int)blockIdx.x;          // natural mapping: XCD column stripes
    const int r0 = (bid >> 4) << 4;           // 64 rowgroups x 16 rows
    const int c0 = (bid & 15) << 6;           // 16 colgroups x 64 cols

    // ---- W1fold -> LDS (once per block) ----
    if (USE_WS) {
        #pragma unroll
        for (int it = 0; it < 10; ++it) {
            const int chunk = it * 4 + wv;               // 39 x 1KB chunks
            if (chunk < 39) {
                const int off = chunk * 1024;
                __builtin_amdgcn_global_load_lds(
                    (const __attribute__((address_space(1))) unsigned int*)
                        ((const char*)ws1 + off + lane * 16),
                    (__attribute__((address_space(3))) unsigned int*)
                        ((char*)w1f + off),
                    16, 0, 0);
            }
        }
    } else {
        for (int u = tid; u < W1PAD; u += 256) {
            const int row = u / W1S, k = u - row * W1S;
            float v = 0.f;
            if (row < 128) {
                if (k < 144) {
                    const int pos = k >> 4, c = k & 15;
                    const int dy = pos / 3, dx = pos - dy * 3;
                    v = (float)((dx - 1) * (1 + (dy == 1))) * W1c[row * 48 + c]
                      + (float)((dy - 1) * (1 + (dx == 1))) * W1c[row * 48 + 16 + c];
                    if (pos == 4) v += W1c[row * 48 + 32 + c];
                } else if (k == 144) {
                    v = b1c[row];
                }
            }
            w1f[u] = (short)bfu(v);
        }
    }

    // ---- staging constants: 792 16B-chunks = 3*256 + 24 (slot 3, tid<24) ----
    // chunk j: pixel pidx=j>>1 (row tr=pidx/66, col tc=pidx%66), half hb=j&1.
    // LDS byte = j*16 ^ ((j&8)<<1)   (the (pidx&4)<<2 swizzle).
    int grow[4], gcol[4], lofs[4];
    #pragma unroll
    for (int s = 0; s < 4; ++s) {
        const int j = tid + 256 * s;
        const int jj = (j < 792) ? j : 791;
        const int pidx = jj >> 1, hb = jj & 1;
        const int tr = pidx / 66, tc = pidx - tr * 66;
        grow[s] = tr;
        gcol[s] = (((c0 - 1 + tc) & (Wc - 1)) << 6) + (hb << 5);   // bytes
        lofs[s] = (jj * 16) ^ ((jj & 8) << 1);                      // bytes
    }
    const bool has3 = (tid < 24);

    // ---- W2 fragments + b2 (registers) ----
    short8 w2f[4];
    if (USE_WS) {
        const unsigned short* wsp = ws2 + p * 128 + 8 * g;
        #pragma unroll
        for (int kc = 0; kc < 4; ++kc)
            w2f[kc] = *reinterpret_cast<const short8*>(wsp + 32 * kc);
    } else {
        #pragma unroll
        for (int kc = 0; kc < 4; ++kc) {
            const float* qp = W2c + p * 128 + 32 * kc + 8 * g;
            const float4 A = *reinterpret_cast<const float4*>(qp);
            const float4 B = *reinterpret_cast<const float4*>(qp + 4);
            uint4 uu{pack2(A.x, A.y), pack2(A.z, A.w), pack2(B.x, B.y), pack2(B.z, B.w)};
            w2f[kc] = __builtin_bit_cast(short8, uu);
        }
    }
    const float4 bv = *reinterpret_cast<const float4*>(b2c + 4 * g);

    // ---- per-lane im2col B addresses (tile-local, constant across t) ----
    // chunk i<4: pos = 2i + (g>>1), ch-half gb = g&1. i=4: pos 8 (g<2);
    // g==2 -> bf16 1.0 at k=144 (b1 fold); g==3 -> zeros.
    const int gb = g & 1;
    int baddr[5];
    #pragma unroll
    for (int i = 0; i < 5; ++i) {
        const int pos = (i < 4) ? (2 * i + (g >> 1)) : 8;
        const int dy = pos / 3, dx = pos - 3 * dy;
        const int pidx = (wv + dy) * 66 + (p + dx);
        baddr[i] = (pidx * 32 + gb * 16) ^ ((pidx & 4) << 2);      // bytes
    }
    const int abase = p * W1S + 8 * g;        // short index into w1f

    int ocol[4];
    #pragma unroll
    for (int pt = 0; pt < 4; ++pt) ocol[pt] = ((c0 + 16 * pt + p) << 6) + (g << 4);

    const char* stby = (const char*)state;
    const char* tby  = (const char*)tile;
    char* outby = (char*)out;

    // ---- prologue: stage tile for t=0 (input rows r0-1 .. r0+4) ----
    {
        float4 sa[4], sb[4];
        #pragma unroll
        for (int s = 0; s < 4; ++s) {
            if (s < 3 || has3) {
                const long sr = (long)((r0 - 1 + grow[s]) & (Hc - 1));
                const char* bp = stby + (sr << 16) + gcol[s];
                sa[s] = *reinterpret_cast<const float4*>(bp);
                sb[s] = *reinterpret_cast<const float4*>(bp + 16);
            }
        }
        #pragma unroll
        for (int s = 0; s < 4; ++s) {
            if (s < 3 || has3) {
                uint4 uu{pack2(sa[s].x, sa[s].y), pack2(sa[s].z, sa[s].w),
                         pack2(sb[s].x, sb[s].y), pack2(sb[s].z, sb[s].w)};
                *reinterpret_cast<uint4*>((char*)tile + lofs[s]) = uu;
            }
        }
    }
    __syncthreads();

    #pragma unroll 1
    for (int t = 0; t < 4; ++t) {
        // (a) compute current tile
        f32x4 acc2[4];
        #pragma unroll
        for (int pt = 0; pt < 4; ++pt) {
            acc2[pt][0] = bv.x; acc2[pt][1] = bv.y; acc2[pt][2] = bv.z; acc2[pt][3] = bv.w;
        }

        #pragma unroll
        for (int half = 0; half < 2; ++half) {
            short8 Ar[4][5];   // 4 hidden-tiles x 5 k-chunks
            #pragma unroll
            for (int tt = 0; tt < 4; ++tt) {
                #pragma unroll
                for (int i = 0; i < 5; ++i) {
                    Ar[tt][i] = *reinterpret_cast<const short8*>(
                        &w1f[abase + (64 * half + 16 * tt) * W1S + 32 * i]);
                }
            }

            __builtin_amdgcn_s_setprio(1);
            #pragma unroll
            for (int pt = 0; pt < 4; ++pt) {
                short8 bf[5];
                #pragma unroll
                for (int i = 0; i < 5; ++i) {
                    if (i < 4) {
                        bf[i] = *reinterpret_cast<const short8*>(tby + baddr[i] + pt * 512);
                    } else {
                        if (g < 2) {
                            bf[i] = *reinterpret_cast<const short8*>(tby + baddr[4] + pt * 512);
                        } else if (g == 2) {
                            uint4 uu{0x3F80u, 0u, 0u, 0u};   // bf16 1.0 @ k=144 (b1)
                            bf[i] = __builtin_bit_cast(short8, uu);
                        } else {
                            uint4 uu{0u, 0u, 0u, 0u};
                            bf[i] = __builtin_bit_cast(short8, uu);
                        }
                    }
                }

                f32x4 h[4];
                #pragma unroll
                for (int tt = 0; tt < 4; ++tt) h[tt] = (f32x4){0.f, 0.f, 0.f, 0.f};
                #pragma unroll
                for (int i = 0; i < 5; ++i) {
                    #pragma unroll
                    for (int tt = 0; tt < 4; ++tt)
                        h[tt] = __builtin_amdgcn_mfma_f32_16x16x32_bf16(Ar[tt][i], bf[i], h[tt], 0, 0, 0);
                }

                // relu -> pack -> in-register transpose -> GEMM2
                #pragma unroll
                for (int pr = 0; pr < 2; ++pr) {
                    const f32x4 ha = h[2 * pr], hc = h[2 * pr + 1];
                    const unsigned Pa0 = pack2(fmaxf(ha[0], 0.f), fmaxf(ha[1], 0.f));
                    const unsigned Pa1 = pack2(fmaxf(ha[2], 0.f), fmaxf(ha[3], 0.f));
                    const unsigned Pb0 = pack2(fmaxf(hc[0], 0.f), fmaxf(hc[1], 0.f));
                    const unsigned Pb1 = pack2(fmaxf(hc[2], 0.f), fmaxf(hc[3], 0.f));
                    unsigned s0, s1, t0, t1, u0, u1, u2, u3;
                    swap32(Pa0, Pb0, s0, s1);
                    swap16(s0, s1, u0, u2);
                    swap32(Pa1, Pb1, t0, t1);
                    swap16(t0, t1, u1, u3);
                    uint4 uu{u0, u1, u2, u3};
                    acc2[pt] = __builtin_amdgcn_mfma_f32_16x16x32_bf16(
                        w2f[2 * half + pr], __builtin_bit_cast(short8, uu), acc2[pt], 0, 0, 0);
                }
            }
            __builtin_amdgcn_s_setprio(0);
        }

        // (b) issue next tile's global loads (live only across stores+barrier)
        float4 sa[4], sb[4];
        if (t < 3) {
            const int rb = r0 + 4 * (t + 1) - 1;
            #pragma unroll
            for (int s = 0; s < 4; ++s) {
                if (s < 3 || has3) {
                    const long sr = (long)((rb + grow[s]) & (Hc - 1));
                    const char* bp = stby + (sr << 16) + gcol[s];
                    sa[s] = *reinterpret_cast<const float4*>(bp);
                    sb[s] = *reinterpret_cast<const float4*>(bp + 16);
                }
            }
        }

        // (c) store output row
        const long orow = (long)(r0 + 4 * t + wv) << 16;
        #pragma unroll
        for (int pt = 0; pt < 4; ++pt) {
            float4 o; o.x = acc2[pt][0]; o.y = acc2[pt][1]; o.z = acc2[pt][2]; o.w = acc2[pt][3];
            *reinterpret_cast<float4*>(outby + orow + ocol[pt]) = o;
        }

        // (d) barrier (tile reads done) -> write next tile -> barrier
        if (t < 3) {
            __syncthreads();
            #pragma unroll
            for (int s = 0; s < 4; ++s) {
                if (s < 3 || has3) {
                    uint4 uu{pack2(sa[s].x, sa[s].y), pack2(sa[s].z, sa[s].w),
                             pack2(sb[s].x, sb[s].y), pack2(sb[s].z, sb[s].w)};
                    *reinterpret_cast<uint4*>((char*)tile + lofs[s]) = uu;
                }
            }
            __syncthreads();
        }
    }
}

extern "C" void kernel_launch(void* const* d_in, const int* in_sizes, int n_in,
                              void* d_out, int out_size, void* d_ws, size_t ws_size,
                              hipStream_t stream) {
    const float* state = (const float*)d_in[0];
    const float* W1c   = (const float*)d_in[1];
    const float* b1c   = (const float*)d_in[2];
    const float* W2c   = (const float*)d_in[3];
    const float* b2c   = (const float*)d_in[4];
    float* out = (float*)d_out;

    unsigned short* ws1 = (unsigned short*)d_ws;
    unsigned short* ws2 = ws1 + W1PAD;
    const size_t ws_needed = (size_t)(W1PAD + 16 * 128) * sizeof(unsigned short);

    if (ws_size >= ws_needed) {
        nca_prep<<<(W1PAD + 16 * 128 + 255) / 256, 256, 0, stream>>>(W1c, b1c, W2c, ws1, ws2);
        nca_main<true><<<1024, 256, 0, stream>>>(state, W1c, b1c, W2c, b2c, ws1, ws2, out);
    } else {
        nca_main<false><<<1024, 256, 0, stream>>>(state, W1c, b1c, W2c, b2c, ws1, ws2, out);
    }
}